// Round 9
// baseline (937.024 us; speedup 1.0000x reference)
//
#include <hip/hip_runtime.h>
#include <hip/hip_bf16.h>
#include <cstdint>
#include <cstddef>

typedef __bf16 bf16;
typedef bf16 bf16x8 __attribute__((ext_vector_type(8)));
typedef float f32x4 __attribute__((ext_vector_type(4)));

#define N_TOK 196
#define DIM_ 384
#define HQKV 2304
#define NH 12
#define NPAD 224          // padded token count (m dim), 7*32
#define B_TOT 256
#define NTILE 13          // q tiles of 16
#define EBF_ELEMS (NH * NTILE * 7 * 64 * 8)   // fragment-packed exp(bias)

// ---------------------------------------------------------------- prep
// ebf[h][tile][ks][lane] = bf16x8, element e = exp(bias[key m, query q])
// with m = 32*ks + (e<4 ? 0:16) + lg*4 + (e&3), q = tile*16 + lr
// (lr=lane&15, lg=lane>>4); 0 when m>=196 or q>=196 (exact mask).
// This is EXACTLY the per-lane factor needed by attn pass 2 -> one
// coalesced 16B load per ks instead of 56 scalar gathers (R8 lesson:
// the gather pipeline's liveness forced a permanent 128-VGPR spill).
__global__ __launch_bounds__(256) void prep_kernel(
    const float* __restrict__ qg, const float* __restrict__ qb,
    const float* __restrict__ qm, const float* __restrict__ qv,
    const float* __restrict__ pg, const float* __restrict__ pb,
    const float* __restrict__ pm, const float* __restrict__ pv,
    const float* __restrict__ abias, const int* __restrict__ idxs,
    float* __restrict__ sqkv, float* __restrict__ bqkv,
    float* __restrict__ sproj, float* __restrict__ bproj,
    bf16* __restrict__ ebf)
{
    int i = blockIdx.x * 256 + threadIdx.x;
    if (i < HQKV) {
        float s = qg[i] * rsqrtf(qv[i] + 1e-5f);
        sqkv[i] = s;
        bqkv[i] = qb[i] - qm[i] * s;
    }
    if (i < DIM_) {
        float s = pg[i] * rsqrtf(pv[i] + 1e-5f);
        sproj[i] = s;
        bproj[i] = pb[i] - pm[i] * s;
    }
    if (i < NH * NTILE * 7 * 64) {
        int lane = i & 63;
        int rem = i >> 6;            // h*91 + tile*7 + ks
        int ks = rem % 7;
        int rem2 = rem / 7;
        int tile = rem2 % NTILE;
        int h = rem2 / NTILE;
        int lr = lane & 15, lg = lane >> 4;
        int q = tile * 16 + lr;
        bf16 o[8];
#pragma unroll
        for (int e = 0; e < 8; ++e) {
            int m = 32 * ks + ((e & 4) << 2) + lg * 4 + (e & 3);
            float v = 0.f;
            if (m < N_TOK && q < N_TOK)
                v = expf(abias[h * N_TOK + idxs[q * N_TOK + m]]);
            o[e] = (bf16)v;
        }
        *(bf16x8*)&ebf[(size_t)i * 8] = *(bf16x8*)o;
    }
}

// ---------------------------------------------------------------- f32 -> bf16 convert
__global__ __launch_bounds__(256) void convert_kernel(
    const float* __restrict__ src, bf16* __restrict__ dst, int n4)
{
    int stride = gridDim.x * 256;
    for (int i = blockIdx.x * 256 + threadIdx.x; i < n4; i += stride) {
        float4 v = ((const float4*)src)[i];
        bf16 o[4] = {(bf16)v.x, (bf16)v.y, (bf16)v.z, (bf16)v.w};
        *(uint2*)&dst[(size_t)i * 4] = *(uint2*)o;
    }
}

// ---------------------------------------------------------------- QKV GEMM (bf16 x bf16)
__global__ __launch_bounds__(256) void qkv_gemm(
    const bf16* __restrict__ x, const bf16* __restrict__ w,
    const float* __restrict__ sq, const float* __restrict__ bq,
    bf16* __restrict__ qkv_c)
{
    __shared__ bf16 As[128 * 40];
    __shared__ bf16 Bs[128 * 40];
    int t = threadIdx.x;
    int m0 = blockIdx.x * 128;
    int n0 = blockIdx.y * 128;
    int lane = t & 63, wid = t >> 6;
    int qr = (wid >> 1) * 64, qc = (wid & 1) * 64;
    int lr = lane & 15, lg = lane >> 4, lk = lg * 8;

    f32x4 acc[4][4];
#pragma unroll
    for (int fi = 0; fi < 4; ++fi)
#pragma unroll
        for (int fj = 0; fj < 4; ++fj)
            acc[fi][fj] = (f32x4){0.f, 0.f, 0.f, 0.f};

    int r = t >> 2, kk = (t & 3) * 8;
    for (int kt = 0; kt < DIM_ / 32; ++kt) {
        int k0 = kt * 32;
        {
            *(bf16x8*)&As[r * 40 + kk] =
                *(const bf16x8*)(x + (size_t)(m0 + r) * DIM_ + k0 + kk);
            *(bf16x8*)&As[(r + 64) * 40 + kk] =
                *(const bf16x8*)(x + (size_t)(m0 + r + 64) * DIM_ + k0 + kk);
            *(bf16x8*)&Bs[r * 40 + kk] =
                *(const bf16x8*)(w + (size_t)(n0 + r) * DIM_ + k0 + kk);
            *(bf16x8*)&Bs[(r + 64) * 40 + kk] =
                *(const bf16x8*)(w + (size_t)(n0 + r + 64) * DIM_ + k0 + kk);
        }
        __syncthreads();
        bf16x8 a[4], b[4];
#pragma unroll
        for (int f = 0; f < 4; ++f) {
            a[f] = *(bf16x8*)&As[(qr + f * 16 + lr) * 40 + lk];
            b[f] = *(bf16x8*)&Bs[(qc + f * 16 + lr) * 40 + lk];
        }
#pragma unroll
        for (int fi = 0; fi < 4; ++fi)
#pragma unroll
            for (int fj = 0; fj < 4; ++fj)
                acc[fi][fj] = __builtin_amdgcn_mfma_f32_16x16x32_bf16(a[fi], b[fj], acc[fi][fj], 0, 0, 0);
        __syncthreads();
    }

#pragma unroll
    for (int fj = 0; fj < 4; ++fj) {
        int col = n0 + qc + fj * 16 + lr;
        float s = sq[col], bb = bq[col];
        int h = col / 192, cc = col - h * 192;
#pragma unroll
        for (int fi = 0; fi < 4; ++fi) {
            int rb = m0 + qr + fi * 16 + lg * 4;
#pragma unroll
            for (int rr = 0; rr < 4; ++rr) {
                int row = rb + rr;
                int bl = row / N_TOK, n = row - bl * N_TOK;
                float v = acc[fi][fj][rr] * s + bb;
                qkv_c[((size_t)(bl * NH + h) * NPAD + n) * 192 + cc] = (bf16)v;
            }
        }
    }
}

// ---------------------------------------------------------------- attention
// qkv_c: [B*12][224][192] bf16 (cols 0:32 q, 32:64 k, 64:192 v)
// ebf: fragment-packed exp(bias) (see prep), attn_c: [B*196][1536] bf16
// Two-pass scores; P packed to bf16 at exp time (multiplicative masked
// bias, one coalesced 16B ebf load per ks); 1/sum deferred + shfl'd to
// C-frag rows (R5 lesson). Masked q-rows (tile 12, lr>=4) get all-zero
// pa -> sum=0 -> rs=inf, but those rows are never stored.
__global__ __launch_bounds__(512) void attn_kernel(
    const bf16* __restrict__ qkv_c, const bf16* __restrict__ ebf,
    bf16* __restrict__ attn_c)
{
    __shared__ bf16 k_s[224 * 40];
    __shared__ bf16 vT_s[128 * 224];   // [d][slot], XOR-swizzled
    int bh = blockIdx.x;
    int bl = bh / NH, h = bh - bl * NH;
    const bf16* base = qkv_c + (size_t)bh * NPAD * 192;
    int t = threadIdx.x;

    // stage K (rows >=196 zeroed)
    for (int c = t; c < 224 * 4; c += 512) {
        int r = c >> 2, g = c & 3;
        bf16x8 v;
        if (r < N_TOK) v = *(const bf16x8*)(base + (size_t)r * 192 + 32 + g * 8);
        else {
#pragma unroll
            for (int j = 0; j < 8; ++j) v[j] = (bf16)0.f;
        }
        *(bf16x8*)&k_s[r * 40 + g * 8] = v;
    }
    // stage V transposed: vT_s[d][slot(m)], slot permutation matches the
    // PV A-fragment k-order: slot = 32*blk + 8*g4 + 4*t16 + r4.
    for (int c = t; c < 56 * 16; c += 512) {
        int rp = c % 56, g = c / 56;
        int r0 = rp * 4;
        bf16x8 v[4];
#pragma unroll
        for (int i = 0; i < 4; ++i) {
            int rr = r0 + i;
            if (rr < N_TOK) v[i] = *(const bf16x8*)(base + (size_t)rr * 192 + 64 + g * 8);
            else {
#pragma unroll
                for (int j = 0; j < 8; ++j) v[i][j] = (bf16)0.f;
            }
        }
        int ml = r0 & 31, blk = r0 >> 5;
        int slot0 = blk * 32 + ((ml & 15) >> 2) * 8 + (ml >> 4) * 4 + (ml & 3);
#pragma unroll
        for (int j = 0; j < 8; ++j) {
            int d = g * 8 + j;
            bf16 w4[4] = {v[0][j], v[1][j], v[2][j], v[3][j]};
            int byte_off = (d * 448 + slot0 * 2) ^ ((d & 7) << 4);
            *(unsigned long long*)((char*)vT_s + byte_off) = *(unsigned long long*)w4;
        }
    }
    __syncthreads();

    int lane = t & 63, wid = t >> 6;
    int lr = lane & 15, lg = lane >> 4, lk = lg * 8;
    const float CSL = 0.17677669529663687f * 1.4426950408889634f; // scl*log2(e)
    int xorv = (lr & 7) << 4;
    const f32x4 z = (f32x4){0.f, 0.f, 0.f, 0.f};

    for (int tile = wid; tile < NTILE; tile += 8) {
        int q0 = tile * 16;
        const bf16* ebt = ebf + (((size_t)h * NTILE + tile) * 7) * 64 * 8;
        // Q fragment (B operand): lane holds q = q0+lr, k contig
        bf16x8 aq = *(const bf16x8*)(base + (size_t)(q0 + lr) * 192 + lk);
        // ---- pass 1: raw-score max only
        float mxr = 0.f;
#pragma unroll
        for (int mt = 0; mt < 14; ++mt) {
            bf16x8 ak = *(const bf16x8*)&k_s[(mt * 16 + lr) * 40 + lk];
            f32x4 Sv = __builtin_amdgcn_mfma_f32_16x16x32_bf16(ak, aq, z, 0, 0, 0);
#pragma unroll
            for (int rr = 0; rr < 4; ++rr) mxr = fmaxf(mxr, Sv[rr]);
        }
        mxr = fmaxf(mxr, __shfl_xor(mxr, 16, 64));
        mxr = fmaxf(mxr, __shfl_xor(mxr, 32, 64));

        // ---- pass 2: recompute S, exp, multiply packed exp(bias), pack
        bf16x8 pa[7];
        float sum = 0.f;
#pragma unroll
        for (int ks = 0; ks < 7; ++ks) {
            bf16x8 ak0 = *(const bf16x8*)&k_s[((2 * ks) * 16 + lr) * 40 + lk];
            bf16x8 ak1 = *(const bf16x8*)&k_s[((2 * ks + 1) * 16 + lr) * 40 + lk];
            f32x4 S0 = __builtin_amdgcn_mfma_f32_16x16x32_bf16(ak0, aq, z, 0, 0, 0);
            f32x4 S1 = __builtin_amdgcn_mfma_f32_16x16x32_bf16(ak1, aq, z, 0, 0, 0);
            bf16x8 ebv = *(const bf16x8*)(ebt + ((size_t)ks * 64 + lane) * 8);
#pragma unroll
            for (int e = 0; e < 4; ++e) {
                float p0 = exp2f((S0[e] - mxr) * CSL) * (float)ebv[e];
                float p1 = exp2f((S1[e] - mxr) * CSL) * (float)ebv[e + 4];
                sum += p0 + p1;
                pa[ks][e] = (bf16)p0;
                pa[ks][e + 4] = (bf16)p1;
            }
        }
        sum += __shfl_xor(sum, 16, 64);
        sum += __shfl_xor(sum, 32, 64);
        float rs = 1.f / sum;
        // acc rows are q = q0+lg*4+rr; their sums live in lanes lr==lg*4+rr
        float rs_r[4];
#pragma unroll
        for (int rr = 0; rr < 4; ++rr)
            rs_r[rr] = __shfl(rs, lg * 4 + rr, 64);

        f32x4 acc[8];
#pragma unroll
        for (int dt = 0; dt < 8; ++dt) acc[dt] = (f32x4){0.f, 0.f, 0.f, 0.f};
#pragma unroll
        for (int ks = 0; ks < 7; ++ks)
#pragma unroll
            for (int dt = 0; dt < 8; ++dt) {
                int byte_off = ((dt * 16 + lr) * 448 + ks * 64 + lg * 16) ^ xorv;
                bf16x8 bv = *(const bf16x8*)((const char*)vT_s + byte_off);
                acc[dt] = __builtin_amdgcn_mfma_f32_16x16x32_bf16(pa[ks], bv, acc[dt], 0, 0, 0);
            }
        // D[q, d]: row = q0 + lg*4 + rr, col = dt*16 + lr; scale by rs_r here
#pragma unroll
        for (int dt = 0; dt < 8; ++dt)
#pragma unroll
            for (int rr = 0; rr < 4; ++rr) {
                int q = q0 + lg * 4 + rr;
                if (q < N_TOK) {
                    float v = acc[dt][rr] * rs_r[rr];
                    float hs = v * fminf(fmaxf(v + 3.f, 0.f), 6.f) * (1.f / 6.f);
                    attn_c[((size_t)bl * N_TOK + q) * 1536 + h * 128 + dt * 16 + lr] = (bf16)hs;
                }
            }
    }
}

// ---------------------------------------------------------------- proj GEMM
__global__ __launch_bounds__(256) void proj_gemm(
    const bf16* __restrict__ aio, const bf16* __restrict__ w,
    const float* __restrict__ sp, const float* __restrict__ bp,
    float* __restrict__ out)
{
    __shared__ bf16 As[128 * 40];
    __shared__ bf16 Bs[128 * 40];
    int t = threadIdx.x;
    int m0 = blockIdx.x * 128;
    int n0 = blockIdx.y * 128;
    int lane = t & 63, wid = t >> 6;
    int qr = (wid >> 1) * 64, qc = (wid & 1) * 64;
    int lr = lane & 15, lg = lane >> 4, lk = lg * 8;

    f32x4 acc[4][4];
#pragma unroll
    for (int fi = 0; fi < 4; ++fi)
#pragma unroll
        for (int fj = 0; fj < 4; ++fj)
            acc[fi][fj] = (f32x4){0.f, 0.f, 0.f, 0.f};

    int r = t >> 2, kk = (t & 3) * 8;
    for (int kt = 0; kt < 1536 / 32; ++kt) {
        int k0 = kt * 32;
        {
            *(bf16x8*)&As[r * 40 + kk] =
                *(const bf16x8*)(aio + (size_t)(m0 + r) * 1536 + k0 + kk);
            *(bf16x8*)&As[(r + 64) * 40 + kk] =
                *(const bf16x8*)(aio + (size_t)(m0 + r + 64) * 1536 + k0 + kk);
            *(bf16x8*)&Bs[r * 40 + kk] =
                *(const bf16x8*)(w + (size_t)(n0 + r) * 1536 + k0 + kk);
            *(bf16x8*)&Bs[(r + 64) * 40 + kk] =
                *(const bf16x8*)(w + (size_t)(n0 + r + 64) * 1536 + k0 + kk);
        }
        __syncthreads();
        bf16x8 a[4], b[4];
#pragma unroll
        for (int f = 0; f < 4; ++f) {
            a[f] = *(bf16x8*)&As[(qr + f * 16 + lr) * 40 + lk];
            b[f] = *(bf16x8*)&Bs[(qc + f * 16 + lr) * 40 + lk];
        }
#pragma unroll
        for (int fi = 0; fi < 4; ++fi)
#pragma unroll
            for (int fj = 0; fj < 4; ++fj)
                acc[fi][fj] = __builtin_amdgcn_mfma_f32_16x16x32_bf16(a[fi], b[fj], acc[fi][fj], 0, 0, 0);
        __syncthreads();
    }

#pragma unroll
    for (int fj = 0; fj < 4; ++fj) {
        int col = n0 + qc + fj * 16 + lr;
        float s = sp[col], bb = bp[col];
#pragma unroll
        for (int fi = 0; fi < 4; ++fi) {
            int rb = m0 + qr + fi * 16 + lg * 4;
#pragma unroll
            for (int rr = 0; rr < 4; ++rr) {
                int row = rb + rr;
                out[(size_t)row * DIM_ + col] = acc[fi][fj][rr] * s + bb;
            }
        }
    }
}

// ---------------------------------------------------------------- launch
extern "C" void kernel_launch(void* const* d_in, const int* in_sizes, int n_in,
                              void* d_out, int out_size, void* d_ws, size_t ws_size,
                              hipStream_t stream)
{
    const float* x          = (const float*)d_in[0];
    const float* qkv_w      = (const float*)d_in[1];
    const float* qkv_gamma  = (const float*)d_in[2];
    const float* qkv_beta   = (const float*)d_in[3];
    const float* qkv_mean   = (const float*)d_in[4];
    const float* qkv_var    = (const float*)d_in[5];
    const float* abias      = (const float*)d_in[6];
    const float* proj_w     = (const float*)d_in[7];
    const float* proj_gamma = (const float*)d_in[8];
    const float* proj_beta  = (const float*)d_in[9];
    const float* proj_mean  = (const float*)d_in[10];
    const float* proj_var   = (const float*)d_in[11];
    const int*   bias_idxs  = (const int*)d_in[12];
    float* out = (float*)d_out;

    char* wp = (char*)d_ws;
    auto alloc = [&](size_t bytes) {
        char* r = wp;
        wp += (bytes + 255) & ~(size_t)255;
        return r;
    };
    float* sqkv  = (float*)alloc((size_t)HQKV * 4);
    float* bqkv  = (float*)alloc((size_t)HQKV * 4);
    float* sproj = (float*)alloc((size_t)DIM_ * 4);
    float* bproj = (float*)alloc((size_t)DIM_ * 4);
    bf16*  ebf   = (bf16*)alloc((size_t)EBF_ELEMS * 2);
    bf16* xb     = (bf16*)alloc((size_t)B_TOT * N_TOK * DIM_ * 2);
    bf16* wb     = (bf16*)alloc((size_t)HQKV * DIM_ * 2);
    bf16* pwb    = (bf16*)alloc((size_t)DIM_ * 1536 * 2);

    size_t fixed_used = (size_t)(wp - (char*)d_ws);
    auto per_chunk = [](int bc) {
        size_t q = ((size_t)bc * NH * NPAD * 192 * 2 + 255) & ~(size_t)255;
        size_t a = ((size_t)bc * N_TOK * 1536 * 2 + 255) & ~(size_t)255;
        return q + a;
    };
    int bchunk = 32;
    const int cands[4] = {256, 128, 64, 32};
    for (int ci = 0; ci < 4; ++ci) {
        if (fixed_used + per_chunk(cands[ci]) <= ws_size) { bchunk = cands[ci]; break; }
    }
    bf16* qkv_c  = (bf16*)alloc((size_t)bchunk * NH * NPAD * 192 * 2);
    bf16* attn_c = (bf16*)alloc((size_t)bchunk * N_TOK * 1536 * 2);

    int prep_grid = (NH * NTILE * 7 * 64 + 255) / 256;  // 273
    prep_kernel<<<prep_grid, 256, 0, stream>>>(
        qkv_gamma, qkv_beta, qkv_mean, qkv_var,
        proj_gamma, proj_beta, proj_mean, proj_var,
        abias, bias_idxs, sqkv, bqkv, sproj, bproj, ebf);

    convert_kernel<<<2048, 256, 0, stream>>>(x, xb, B_TOT * N_TOK * DIM_ / 4);
    convert_kernel<<<512, 256, 0, stream>>>(qkv_w, wb, HQKV * DIM_ / 4);
    convert_kernel<<<512, 256, 0, stream>>>(proj_w, pwb, DIM_ * 1536 / 4);

    int mrows = bchunk * N_TOK;
    for (int c = 0; c < B_TOT / bchunk; ++c) {
        const bf16* xc = xb + (size_t)c * bchunk * N_TOK * DIM_;
        float* oc = out + (size_t)c * bchunk * N_TOK * DIM_;
        qkv_gemm<<<dim3(mrows / 128, HQKV / 128), 256, 0, stream>>>(
            xc, wb, sqkv, bqkv, qkv_c);
        attn_kernel<<<dim3(bchunk * NH), 512, 0, stream>>>(qkv_c, ebf, attn_c);
        proj_gemm<<<dim3(mrows / 128, DIM_ / 128), 256, 0, stream>>>(
            attn_c, pwb, sproj, bproj, oc);
    }
}

// Round 10
// 933.567 us; speedup vs baseline: 1.0037x; 1.0037x over previous
//
#include <hip/hip_runtime.h>
#include <hip/hip_bf16.h>
#include <cstdint>
#include <cstddef>

typedef __bf16 bf16;
typedef bf16 bf16x8 __attribute__((ext_vector_type(8)));
typedef float f32x4 __attribute__((ext_vector_type(4)));

#define N_TOK 196
#define DIM_ 384
#define HQKV 2304
#define NH 12
#define NPAD 224          // padded token count (m dim), 7*32
#define B_TOT 256
#define NTILE 13          // q tiles of 16
#define EBF_ELEMS (NH * NTILE * 7 * 64 * 8)   // fragment-packed exp(bias)

// ---------------------------------------------------------------- prep
// ebf[h][tile][ks][lane] = bf16x8, element e = exp(bias[key m, query q])
// with m = 32*ks + (e<4 ? 0:16) + lg*4 + (e&3), q = tile*16 + lr
// (lr=lane&15, lg=lane>>4); 0 when m>=196 or q>=196 (exact mask).
__global__ __launch_bounds__(256) void prep_kernel(
    const float* __restrict__ qg, const float* __restrict__ qb,
    const float* __restrict__ qm, const float* __restrict__ qv,
    const float* __restrict__ pg, const float* __restrict__ pb,
    const float* __restrict__ pm, const float* __restrict__ pv,
    const float* __restrict__ abias, const int* __restrict__ idxs,
    float* __restrict__ sqkv, float* __restrict__ bqkv,
    float* __restrict__ sproj, float* __restrict__ bproj,
    bf16* __restrict__ ebf)
{
    int i = blockIdx.x * 256 + threadIdx.x;
    if (i < HQKV) {
        float s = qg[i] * rsqrtf(qv[i] + 1e-5f);
        sqkv[i] = s;
        bqkv[i] = qb[i] - qm[i] * s;
    }
    if (i < DIM_) {
        float s = pg[i] * rsqrtf(pv[i] + 1e-5f);
        sproj[i] = s;
        bproj[i] = pb[i] - pm[i] * s;
    }
    if (i < NH * NTILE * 7 * 64) {
        int lane = i & 63;
        int rem = i >> 6;            // h*91 + tile*7 + ks
        int ks = rem % 7;
        int rem2 = rem / 7;
        int tile = rem2 % NTILE;
        int h = rem2 / NTILE;
        int lr = lane & 15, lg = lane >> 4;
        int q = tile * 16 + lr;
        bf16 o[8];
#pragma unroll
        for (int e = 0; e < 8; ++e) {
            int m = 32 * ks + ((e & 4) << 2) + lg * 4 + (e & 3);
            float v = 0.f;
            if (m < N_TOK && q < N_TOK)
                v = expf(abias[h * N_TOK + idxs[q * N_TOK + m]]);
            o[e] = (bf16)v;
        }
        *(bf16x8*)&ebf[(size_t)i * 8] = *(bf16x8*)o;
    }
}

// ---------------------------------------------------------------- f32 -> bf16 convert
__global__ __launch_bounds__(256) void convert_kernel(
    const float* __restrict__ src, bf16* __restrict__ dst, int n4)
{
    int stride = gridDim.x * 256;
    for (int i = blockIdx.x * 256 + threadIdx.x; i < n4; i += stride) {
        float4 v = ((const float4*)src)[i];
        bf16 o[4] = {(bf16)v.x, (bf16)v.y, (bf16)v.z, (bf16)v.w};
        *(uint2*)&dst[(size_t)i * 4] = *(uint2*)o;
    }
}

// ---------------------------------------------------------------- QKV GEMM (bf16 x bf16)
__global__ __launch_bounds__(256) void qkv_gemm(
    const bf16* __restrict__ x, const bf16* __restrict__ w,
    const float* __restrict__ sq, const float* __restrict__ bq,
    bf16* __restrict__ qkv_c)
{
    __shared__ bf16 As[128 * 40];
    __shared__ bf16 Bs[128 * 40];
    int t = threadIdx.x;
    int m0 = blockIdx.x * 128;
    int n0 = blockIdx.y * 128;
    int lane = t & 63, wid = t >> 6;
    int qr = (wid >> 1) * 64, qc = (wid & 1) * 64;
    int lr = lane & 15, lg = lane >> 4, lk = lg * 8;

    f32x4 acc[4][4];
#pragma unroll
    for (int fi = 0; fi < 4; ++fi)
#pragma unroll
        for (int fj = 0; fj < 4; ++fj)
            acc[fi][fj] = (f32x4){0.f, 0.f, 0.f, 0.f};

    int r = t >> 2, kk = (t & 3) * 8;
    for (int kt = 0; kt < DIM_ / 32; ++kt) {
        int k0 = kt * 32;
        {
            *(bf16x8*)&As[r * 40 + kk] =
                *(const bf16x8*)(x + (size_t)(m0 + r) * DIM_ + k0 + kk);
            *(bf16x8*)&As[(r + 64) * 40 + kk] =
                *(const bf16x8*)(x + (size_t)(m0 + r + 64) * DIM_ + k0 + kk);
            *(bf16x8*)&Bs[r * 40 + kk] =
                *(const bf16x8*)(w + (size_t)(n0 + r) * DIM_ + k0 + kk);
            *(bf16x8*)&Bs[(r + 64) * 40 + kk] =
                *(const bf16x8*)(w + (size_t)(n0 + r + 64) * DIM_ + k0 + kk);
        }
        __syncthreads();
        bf16x8 a[4], b[4];
#pragma unroll
        for (int f = 0; f < 4; ++f) {
            a[f] = *(bf16x8*)&As[(qr + f * 16 + lr) * 40 + lk];
            b[f] = *(bf16x8*)&Bs[(qc + f * 16 + lr) * 40 + lk];
        }
#pragma unroll
        for (int fi = 0; fi < 4; ++fi)
#pragma unroll
            for (int fj = 0; fj < 4; ++fj)
                acc[fi][fj] = __builtin_amdgcn_mfma_f32_16x16x32_bf16(a[fi], b[fj], acc[fi][fj], 0, 0, 0);
        __syncthreads();
    }

#pragma unroll
    for (int fj = 0; fj < 4; ++fj) {
        int col = n0 + qc + fj * 16 + lr;
        float s = sq[col], bb = bq[col];
        int h = col / 192, cc = col - h * 192;
#pragma unroll
        for (int fi = 0; fi < 4; ++fi) {
            int rb = m0 + qr + fi * 16 + lg * 4;
#pragma unroll
            for (int rr = 0; rr < 4; ++rr) {
                int row = rb + rr;
                int bl = row / N_TOK, n = row - bl * N_TOK;
                float v = acc[fi][fj][rr] * s + bb;
                qkv_c[((size_t)(bl * NH + h) * NPAD + n) * 192 + cc] = (bf16)v;
            }
        }
    }
}

// ---------------------------------------------------------------- attention
// qkv_c: [bchunk*12][224][192] bf16 (cols 0:32 q, 32:64 k, 64:192 v)
// ebf: fragment-packed exp(bias) (see prep), attn_c: [bchunk*196][1536] bf16
// R9 post-mortem: NO spill (R8 allowed 256 VGPR, compiler still chose 128).
// The 870MB/dispatch at bchunk=256 was capacity traffic: qkv_c(264MB)+
// attn_c(154MB) > 256MB L3 -> compulsory streams + attn_c write-allocate
// + qkv_c dirty write-back. Fix is bchunk=64 (launch side), not the kernel.
__global__ __launch_bounds__(512) void attn_kernel(
    const bf16* __restrict__ qkv_c, const bf16* __restrict__ ebf,
    bf16* __restrict__ attn_c)
{
    __shared__ bf16 k_s[224 * 40];
    __shared__ bf16 vT_s[128 * 224];   // [d][slot], XOR-swizzled
    int bh = blockIdx.x;
    int bl = bh / NH, h = bh - bl * NH;
    const bf16* base = qkv_c + (size_t)bh * NPAD * 192;
    int t = threadIdx.x;

    // stage K (rows >=196 zeroed)
    for (int c = t; c < 224 * 4; c += 512) {
        int r = c >> 2, g = c & 3;
        bf16x8 v;
        if (r < N_TOK) v = *(const bf16x8*)(base + (size_t)r * 192 + 32 + g * 8);
        else {
#pragma unroll
            for (int j = 0; j < 8; ++j) v[j] = (bf16)0.f;
        }
        *(bf16x8*)&k_s[r * 40 + g * 8] = v;
    }
    // stage V transposed: vT_s[d][slot(m)], slot permutation matches the
    // PV A-fragment k-order: slot = 32*blk + 8*g4 + 4*t16 + r4.
    for (int c = t; c < 56 * 16; c += 512) {
        int rp = c % 56, g = c / 56;
        int r0 = rp * 4;
        bf16x8 v[4];
#pragma unroll
        for (int i = 0; i < 4; ++i) {
            int rr = r0 + i;
            if (rr < N_TOK) v[i] = *(const bf16x8*)(base + (size_t)rr * 192 + 64 + g * 8);
            else {
#pragma unroll
                for (int j = 0; j < 8; ++j) v[i][j] = (bf16)0.f;
            }
        }
        int ml = r0 & 31, blk = r0 >> 5;
        int slot0 = blk * 32 + ((ml & 15) >> 2) * 8 + (ml >> 4) * 4 + (ml & 3);
#pragma unroll
        for (int j = 0; j < 8; ++j) {
            int d = g * 8 + j;
            bf16 w4[4] = {v[0][j], v[1][j], v[2][j], v[3][j]};
            int byte_off = (d * 448 + slot0 * 2) ^ ((d & 7) << 4);
            *(unsigned long long*)((char*)vT_s + byte_off) = *(unsigned long long*)w4;
        }
    }
    __syncthreads();

    int lane = t & 63, wid = t >> 6;
    int lr = lane & 15, lg = lane >> 4, lk = lg * 8;
    const float CSL = 0.17677669529663687f * 1.4426950408889634f; // scl*log2(e)
    int xorv = (lr & 7) << 4;
    const f32x4 z = (f32x4){0.f, 0.f, 0.f, 0.f};

    for (int tile = wid; tile < NTILE; tile += 8) {
        int q0 = tile * 16;
        const bf16* ebt = ebf + (((size_t)h * NTILE + tile) * 7) * 64 * 8;
        // Q fragment (B operand): lane holds q = q0+lr, k contig
        bf16x8 aq = *(const bf16x8*)(base + (size_t)(q0 + lr) * 192 + lk);
        // ---- pass 1: raw-score max only
        float mxr = 0.f;
#pragma unroll
        for (int mt = 0; mt < 14; ++mt) {
            bf16x8 ak = *(const bf16x8*)&k_s[(mt * 16 + lr) * 40 + lk];
            f32x4 Sv = __builtin_amdgcn_mfma_f32_16x16x32_bf16(ak, aq, z, 0, 0, 0);
#pragma unroll
            for (int rr = 0; rr < 4; ++rr) mxr = fmaxf(mxr, Sv[rr]);
        }
        mxr = fmaxf(mxr, __shfl_xor(mxr, 16, 64));
        mxr = fmaxf(mxr, __shfl_xor(mxr, 32, 64));

        // ---- pass 2: recompute S, exp, multiply packed exp(bias), pack
        bf16x8 pa[7];
        float sum = 0.f;
#pragma unroll
        for (int ks = 0; ks < 7; ++ks) {
            bf16x8 ak0 = *(const bf16x8*)&k_s[((2 * ks) * 16 + lr) * 40 + lk];
            bf16x8 ak1 = *(const bf16x8*)&k_s[((2 * ks + 1) * 16 + lr) * 40 + lk];
            f32x4 S0 = __builtin_amdgcn_mfma_f32_16x16x32_bf16(ak0, aq, z, 0, 0, 0);
            f32x4 S1 = __builtin_amdgcn_mfma_f32_16x16x32_bf16(ak1, aq, z, 0, 0, 0);
            bf16x8 ebv = *(const bf16x8*)(ebt + ((size_t)ks * 64 + lane) * 8);
#pragma unroll
            for (int e = 0; e < 4; ++e) {
                float p0 = exp2f((S0[e] - mxr) * CSL) * (float)ebv[e];
                float p1 = exp2f((S1[e] - mxr) * CSL) * (float)ebv[e + 4];
                sum += p0 + p1;
                pa[ks][e] = (bf16)p0;
                pa[ks][e + 4] = (bf16)p1;
            }
        }
        sum += __shfl_xor(sum, 16, 64);
        sum += __shfl_xor(sum, 32, 64);
        float rs = 1.f / sum;
        // acc rows are q = q0+lg*4+rr; their sums live in lanes lr==lg*4+rr
        float rs_r[4];
#pragma unroll
        for (int rr = 0; rr < 4; ++rr)
            rs_r[rr] = __shfl(rs, lg * 4 + rr, 64);

        f32x4 acc[8];
#pragma unroll
        for (int dt = 0; dt < 8; ++dt) acc[dt] = (f32x4){0.f, 0.f, 0.f, 0.f};
#pragma unroll
        for (int ks = 0; ks < 7; ++ks)
#pragma unroll
            for (int dt = 0; dt < 8; ++dt) {
                int byte_off = ((dt * 16 + lr) * 448 + ks * 64 + lg * 16) ^ xorv;
                bf16x8 bv = *(const bf16x8*)((const char*)vT_s + byte_off);
                acc[dt] = __builtin_amdgcn_mfma_f32_16x16x32_bf16(pa[ks], bv, acc[dt], 0, 0, 0);
            }
        // D[q, d]: row = q0 + lg*4 + rr, col = dt*16 + lr; scale by rs_r here
#pragma unroll
        for (int dt = 0; dt < 8; ++dt)
#pragma unroll
            for (int rr = 0; rr < 4; ++rr) {
                int q = q0 + lg * 4 + rr;
                if (q < N_TOK) {
                    float v = acc[dt][rr] * rs_r[rr];
                    float hs = v * fminf(fmaxf(v + 3.f, 0.f), 6.f) * (1.f / 6.f);
                    attn_c[((size_t)bl * N_TOK + q) * 1536 + h * 128 + dt * 16 + lr] = (bf16)hs;
                }
            }
    }
}

// ---------------------------------------------------------------- proj GEMM
__global__ __launch_bounds__(256) void proj_gemm(
    const bf16* __restrict__ aio, const bf16* __restrict__ w,
    const float* __restrict__ sp, const float* __restrict__ bp,
    float* __restrict__ out)
{
    __shared__ bf16 As[128 * 40];
    __shared__ bf16 Bs[128 * 40];
    int t = threadIdx.x;
    int m0 = blockIdx.x * 128;
    int n0 = blockIdx.y * 128;
    int lane = t & 63, wid = t >> 6;
    int qr = (wid >> 1) * 64, qc = (wid & 1) * 64;
    int lr = lane & 15, lg = lane >> 4, lk = lg * 8;

    f32x4 acc[4][4];
#pragma unroll
    for (int fi = 0; fi < 4; ++fi)
#pragma unroll
        for (int fj = 0; fj < 4; ++fj)
            acc[fi][fj] = (f32x4){0.f, 0.f, 0.f, 0.f};

    int r = t >> 2, kk = (t & 3) * 8;
    for (int kt = 0; kt < 1536 / 32; ++kt) {
        int k0 = kt * 32;
        {
            *(bf16x8*)&As[r * 40 + kk] =
                *(const bf16x8*)(aio + (size_t)(m0 + r) * 1536 + k0 + kk);
            *(bf16x8*)&As[(r + 64) * 40 + kk] =
                *(const bf16x8*)(aio + (size_t)(m0 + r + 64) * 1536 + k0 + kk);
            *(bf16x8*)&Bs[r * 40 + kk] =
                *(const bf16x8*)(w + (size_t)(n0 + r) * 1536 + k0 + kk);
            *(bf16x8*)&Bs[(r + 64) * 40 + kk] =
                *(const bf16x8*)(w + (size_t)(n0 + r + 64) * 1536 + k0 + kk);
        }
        __syncthreads();
        bf16x8 a[4], b[4];
#pragma unroll
        for (int f = 0; f < 4; ++f) {
            a[f] = *(bf16x8*)&As[(qr + f * 16 + lr) * 40 + lk];
            b[f] = *(bf16x8*)&Bs[(qc + f * 16 + lr) * 40 + lk];
        }
#pragma unroll
        for (int fi = 0; fi < 4; ++fi)
#pragma unroll
            for (int fj = 0; fj < 4; ++fj)
                acc[fi][fj] = __builtin_amdgcn_mfma_f32_16x16x32_bf16(a[fi], b[fj], acc[fi][fj], 0, 0, 0);
        __syncthreads();
    }

#pragma unroll
    for (int fj = 0; fj < 4; ++fj) {
        int col = n0 + qc + fj * 16 + lr;
        float s = sp[col], bb = bp[col];
#pragma unroll
        for (int fi = 0; fi < 4; ++fi) {
            int rb = m0 + qr + fi * 16 + lg * 4;
#pragma unroll
            for (int rr = 0; rr < 4; ++rr) {
                int row = rb + rr;
                // final output, never re-read -> nontemporal (skip L2/L3
                // allocate; avoids polluting the L3 working set)
                __builtin_nontemporal_store(acc[fi][fj][rr] * s + bb,
                                            &out[(size_t)row * DIM_ + col]);
            }
        }
    }
}

// ---------------------------------------------------------------- launch
extern "C" void kernel_launch(void* const* d_in, const int* in_sizes, int n_in,
                              void* d_out, int out_size, void* d_ws, size_t ws_size,
                              hipStream_t stream)
{
    const float* x          = (const float*)d_in[0];
    const float* qkv_w      = (const float*)d_in[1];
    const float* qkv_gamma  = (const float*)d_in[2];
    const float* qkv_beta   = (const float*)d_in[3];
    const float* qkv_mean   = (const float*)d_in[4];
    const float* qkv_var    = (const float*)d_in[5];
    const float* abias      = (const float*)d_in[6];
    const float* proj_w     = (const float*)d_in[7];
    const float* proj_gamma = (const float*)d_in[8];
    const float* proj_beta  = (const float*)d_in[9];
    const float* proj_mean  = (const float*)d_in[10];
    const float* proj_var   = (const float*)d_in[11];
    const int*   bias_idxs  = (const int*)d_in[12];
    float* out = (float*)d_out;

    char* wp = (char*)d_ws;
    auto alloc = [&](size_t bytes) {
        char* r = wp;
        wp += (bytes + 255) & ~(size_t)255;
        return r;
    };
    float* sqkv  = (float*)alloc((size_t)HQKV * 4);
    float* bqkv  = (float*)alloc((size_t)HQKV * 4);
    float* sproj = (float*)alloc((size_t)DIM_ * 4);
    float* bproj = (float*)alloc((size_t)DIM_ * 4);
    bf16*  ebf   = (bf16*)alloc((size_t)EBF_ELEMS * 2);
    bf16* xb     = (bf16*)alloc((size_t)B_TOT * N_TOK * DIM_ * 2);
    bf16* wb     = (bf16*)alloc((size_t)HQKV * DIM_ * 2);
    bf16* pwb    = (bf16*)alloc((size_t)DIM_ * 1536 * 2);

    // bchunk=64 keeps the per-chunk intermediates (qkv_c 66MB + attn_c 39MB)
    // L3-resident (R9 lesson: bchunk=256's 418MB working set > 256MB L3 cost
    // ~600MB/launch of capacity traffic) while all grids stay >= 256 blocks
    // (R1 lesson: bchunk=32's proj grid of 147 starves the GPU).
    size_t fixed_used = (size_t)(wp - (char*)d_ws);
    auto per_chunk = [](int bc) {
        size_t q = ((size_t)bc * NH * NPAD * 192 * 2 + 255) & ~(size_t)255;
        size_t a = ((size_t)bc * N_TOK * 1536 * 2 + 255) & ~(size_t)255;
        return q + a;
    };
    int bchunk = 32;
    const int cands[2] = {64, 32};
    for (int ci = 0; ci < 2; ++ci) {
        if (fixed_used + per_chunk(cands[ci]) <= ws_size) { bchunk = cands[ci]; break; }
    }
    bf16* qkv_c  = (bf16*)alloc((size_t)bchunk * NH * NPAD * 192 * 2);
    bf16* attn_c = (bf16*)alloc((size_t)bchunk * N_TOK * 1536 * 2);

    int prep_grid = (NH * NTILE * 7 * 64 + 255) / 256;  // 273
    prep_kernel<<<prep_grid, 256, 0, stream>>>(
        qkv_gamma, qkv_beta, qkv_mean, qkv_var,
        proj_gamma, proj_beta, proj_mean, proj_var,
        abias, bias_idxs, sqkv, bqkv, sproj, bproj, ebf);

    convert_kernel<<<2048, 256, 0, stream>>>(x, xb, B_TOT * N_TOK * DIM_ / 4);
    convert_kernel<<<512, 256, 0, stream>>>(qkv_w, wb, HQKV * DIM_ / 4);
    convert_kernel<<<512, 256, 0, stream>>>(proj_w, pwb, DIM_ * 1536 / 4);

    int mrows = bchunk * N_TOK;
    for (int c = 0; c < B_TOT / bchunk; ++c) {
        const bf16* xc = xb + (size_t)c * bchunk * N_TOK * DIM_;
        float* oc = out + (size_t)c * bchunk * N_TOK * DIM_;
        qkv_gemm<<<dim3(mrows / 128, HQKV / 128), 256, 0, stream>>>(
            xc, wb, sqkv, bqkv, qkv_c);
        attn_kernel<<<dim3(bchunk * NH), 512, 0, stream>>>(qkv_c, ebf, attn_c);
        proj_gemm<<<dim3(mrows / 128, DIM_ / 128), 256, 0, stream>>>(
            attn_c, pwb, sproj, bproj, oc);
    }
}